// Round 1
// baseline (219.585 us; speedup 1.0000x reference)
//
#include <hip/hip_runtime.h>

// NT-Xent: BATCH=4096, DIM=512, TEMP=0.5
// loss = mean_i [ log(sum_{j!=i} exp(2*cos(z_i,z_j))) - 2*cos(z_i, z_partner) ]
// Strategy: normalize rows to unit norm in fp32, cast to bf16, compute the
// 8192x8192x512 Gram matrix with bf16 MFMA, fuse exp+row-sum in the epilogue.
// No max-subtraction needed: logits bounded by |2*cos| <= 2.

#define NROWS 8192
#define HALF_N 4096
#define KD 512
#define TILE 128
#define BK 64

typedef __bf16 bf16;
typedef __attribute__((ext_vector_type(8))) __bf16 bf16x8;
typedef __attribute__((ext_vector_type(4))) float f32x4;

// ---------------- normalize: z (fp32) -> zhat (bf16, unit rows) ----------------
__global__ __launch_bounds__(256) void nt_normalize(const float* __restrict__ zi,
                                                    const float* __restrict__ zj,
                                                    bf16* __restrict__ zhat) {
  const int row = blockIdx.x;
  const float* src = (row < HALF_N) ? (zi + (size_t)row * KD)
                                    : (zj + (size_t)(row - HALF_N) * KD);
  const int t = threadIdx.x;                 // 256 threads, 2 floats each
  float2 v = ((const float2*)src)[t];
  float ss = v.x * v.x + v.y * v.y;
#pragma unroll
  for (int m = 1; m < 64; m <<= 1) ss += __shfl_xor(ss, m);
  __shared__ float wsum[4];
  if ((t & 63) == 0) wsum[t >> 6] = ss;
  __syncthreads();
  const float tot = wsum[0] + wsum[1] + wsum[2] + wsum[3];
  const float inv = rsqrtf(tot);             // norms ~22.6, EPS irrelevant
  bf16* dst = zhat + (size_t)row * KD + 2 * t;
  dst[0] = (bf16)(v.x * inv);
  dst[1] = (bf16)(v.y * inv);
}

// ---------------- GEMM + exp row-sum ----------------
// 128x128 tile per block, 4 waves in 2x2, each wave 4x4 MFMA tiles of 16x16.
// rowsum[i] += sum_j exp(2 * dot(zhat_i, zhat_j))  (diagonal included; removed
// in finalize by subtracting exp(2*||zhat_i||^2) computed from the same bf16).
__global__ __launch_bounds__(256) void nt_gemm(const bf16* __restrict__ zhat,
                                               float* __restrict__ rowsum) {
  __shared__ __attribute__((aligned(16))) bf16 lA[TILE * BK];
  __shared__ __attribute__((aligned(16))) bf16 lB[TILE * BK];
  __shared__ float lrow[TILE];

  const int tm = blockIdx.y, tn = blockIdx.x;
  const int t = threadIdx.x;
  const int wave = t >> 6, lane = t & 63;
  const int wm = wave >> 1, wn = wave & 1;
  const int c16 = lane & 15, quad = lane >> 4;

  const int rowA = tm * TILE, rowB = tn * TILE;

  f32x4 acc[4][4] = {};

  for (int k0 = 0; k0 < KD; k0 += BK) {
    __syncthreads();
    // stage 128x64 bf16 tiles: 1024 chunks of 16B each per tile, 4 per thread
#pragma unroll
    for (int it = 0; it < 4; ++it) {
      const int chunk = it * 256 + t;
      const int r = chunk >> 3, c = (chunk & 7) << 3;
      *(bf16x8*)&lA[chunk * 8] =
          *(const bf16x8*)&zhat[(size_t)(rowA + r) * KD + k0 + c];
      *(bf16x8*)&lB[chunk * 8] =
          *(const bf16x8*)&zhat[(size_t)(rowB + r) * KD + k0 + c];
    }
    __syncthreads();
#pragma unroll
    for (int kk = 0; kk < BK; kk += 32) {
      bf16x8 af[4], bg[4];
#pragma unroll
      for (int mi = 0; mi < 4; ++mi)
        af[mi] = *(const bf16x8*)&lA[(wm * 64 + mi * 16 + c16) * BK + kk + quad * 8];
#pragma unroll
      for (int ni = 0; ni < 4; ++ni)
        bg[ni] = *(const bf16x8*)&lB[(wn * 64 + ni * 16 + c16) * BK + kk + quad * 8];
#pragma unroll
      for (int mi = 0; mi < 4; ++mi)
#pragma unroll
        for (int ni = 0; ni < 4; ++ni)
          acc[mi][ni] = __builtin_amdgcn_mfma_f32_16x16x32_bf16(
              af[mi], bg[ni], acc[mi][ni], 0, 0, 0);
    }
  }

  // epilogue: e = exp(2*sim); reduce over this block's 128 columns per row
  if (t < TILE) lrow[t] = 0.f;
  __syncthreads();
#pragma unroll
  for (int mi = 0; mi < 4; ++mi) {
#pragma unroll
    for (int r = 0; r < 4; ++r) {
      float e = 0.f;
#pragma unroll
      for (int ni = 0; ni < 4; ++ni) e += __expf(2.0f * acc[mi][ni][r]);
      // sum across the 16 lanes of this quad (the 16 columns of the MFMA tile)
      e += __shfl_xor(e, 1);
      e += __shfl_xor(e, 2);
      e += __shfl_xor(e, 4);
      e += __shfl_xor(e, 8);
      if (c16 == 0) atomicAdd(&lrow[wm * 64 + mi * 16 + quad * 4 + r], e);
    }
  }
  __syncthreads();
  if (t < TILE) atomicAdd(&rowsum[rowA + t], lrow[t]);
}

// ---------------- finalize: loss contributions ----------------
// one wave handles 16 rows; per row: selfdot (diag removal) + posdot
__global__ __launch_bounds__(256) void nt_finalize(const bf16* __restrict__ zhat,
                                                   const float* __restrict__ rowsum,
                                                   float* __restrict__ acc) {
  const int t = threadIdx.x;
  const int wave = t >> 6, lane = t & 63;
  float local = 0.f;
  for (int r = 0; r < 16; ++r) {
    const int i = (blockIdx.x * 4 + wave) * 16 + r;
    const int p = (i + HALF_N) & (NROWS - 1);
    bf16x8 av = *(const bf16x8*)(zhat + (size_t)i * KD + lane * 8);
    bf16x8 bv = *(const bf16x8*)(zhat + (size_t)p * KD + lane * 8);
    float sd = 0.f, cd = 0.f;
#pragma unroll
    for (int j = 0; j < 8; ++j) {
      const float x = (float)av[j];
      sd += x * x;
      cd += x * (float)bv[j];
    }
#pragma unroll
    for (int m = 1; m < 64; m <<= 1) {
      sd += __shfl_xor(sd, m);
      cd += __shfl_xor(cd, m);
    }
    if (lane == 0)
      local += logf(rowsum[i] - __expf(2.f * sd)) - 2.f * cd;
  }
  __shared__ float bsum[4];
  if (lane == 0) bsum[wave] = local;
  __syncthreads();
  if (t == 0) atomicAdd(acc, bsum[0] + bsum[1] + bsum[2] + bsum[3]);
}

__global__ void nt_writeout(const float* __restrict__ acc, float* __restrict__ out) {
  out[0] = acc[0] * (1.0f / NROWS);
}

extern "C" void kernel_launch(void* const* d_in, const int* in_sizes, int n_in,
                              void* d_out, int out_size, void* d_ws, size_t ws_size,
                              hipStream_t stream) {
  const float* zi = (const float*)d_in[0];
  const float* zj = (const float*)d_in[1];
  float* out = (float*)d_out;

  // ws layout: zhat (8192*512 bf16 = 8 MB) | rowsum (8192 f32) | acc (1 f32)
  bf16* zhat = (bf16*)d_ws;
  float* rowsum = (float*)((char*)d_ws + (size_t)NROWS * KD * sizeof(bf16));
  float* acc = rowsum + NROWS;

  hipMemsetAsync(rowsum, 0, (NROWS + 1) * sizeof(float), stream);
  nt_normalize<<<NROWS, 256, 0, stream>>>(zi, zj, zhat);
  dim3 grid(NROWS / TILE, NROWS / TILE);
  nt_gemm<<<grid, 256, 0, stream>>>(zhat, rowsum);
  nt_finalize<<<NROWS / (4 * 16), 256, 0, stream>>>(zhat, rowsum, acc);
  nt_writeout<<<1, 1, 0, stream>>>(acc, out);
}

// Round 2
// 191.017 us; speedup vs baseline: 1.1496x; 1.1496x over previous
//
#include <hip/hip_runtime.h>

// NT-Xent: BATCH=4096, DIM=512, TEMP=0.5
// loss = mean_i [ log(sum_{j!=i} exp(2*cos(z_i,z_j))) - 2*cos(z_i, z_partner) ]
// R2: GEMM staging via global_load_lds (width=16) + XOR-swizzled LDS layout
// to kill the 16-way ds_read bank conflicts seen in R1 (SQ_LDS_BANK_CONFLICT=2.5e7).

#define NROWS 8192
#define HALF_N 4096
#define KD 512
#define TILE 128
#define BK 64

typedef __bf16 bf16;
typedef __attribute__((ext_vector_type(8))) __bf16 bf16x8;
typedef __attribute__((ext_vector_type(4))) float f32x4;

__device__ inline void load16_to_lds(const bf16* g, bf16* l) {
  __builtin_amdgcn_global_load_lds((const __attribute__((address_space(1))) void*)g,
                                   (__attribute__((address_space(3))) void*)l,
                                   16, 0, 0);
}

// ---------------- normalize: z (fp32) -> zhat (bf16, unit rows) ----------------
__global__ __launch_bounds__(256) void nt_normalize(const float* __restrict__ zi,
                                                    const float* __restrict__ zj,
                                                    bf16* __restrict__ zhat) {
  const int row = blockIdx.x;
  const float* src = (row < HALF_N) ? (zi + (size_t)row * KD)
                                    : (zj + (size_t)(row - HALF_N) * KD);
  const int t = threadIdx.x;                 // 256 threads, 2 floats each
  float2 v = ((const float2*)src)[t];
  float ss = v.x * v.x + v.y * v.y;
#pragma unroll
  for (int m = 1; m < 64; m <<= 1) ss += __shfl_xor(ss, m);
  __shared__ float wsum[4];
  if ((t & 63) == 0) wsum[t >> 6] = ss;
  __syncthreads();
  const float tot = wsum[0] + wsum[1] + wsum[2] + wsum[3];
  const float inv = rsqrtf(tot);             // norms ~22.6, EPS irrelevant
  bf16* dst = zhat + (size_t)row * KD + 2 * t;
  dst[0] = (bf16)(v.x * inv);
  dst[1] = (bf16)(v.y * inv);
}

// ---------------- GEMM + exp row-sum ----------------
// 128x128 tile per block, 4 waves in 2x2, each wave 4x4 MFMA tiles of 16x16.
// LDS tiles hold 16B chunks; chunk (r,c) of the 128x8-chunk tile lives at
// position r*8 + (c ^ (r&7)) — XOR swizzle so fragment reads (16 lanes with
// distinct r, same c) spread across all 32 banks (2-way aliasing = free).
// Staged with global_load_lds: wave-uniform LDS base + lane*16; each lane
// fetches the global chunk that belongs at its LDS slot.
__global__ __launch_bounds__(256) void nt_gemm(const bf16* __restrict__ zhat,
                                               float* __restrict__ rowsum) {
  __shared__ __attribute__((aligned(16))) bf16 lA[TILE * BK];
  __shared__ __attribute__((aligned(16))) bf16 lB[TILE * BK];
  __shared__ float lrow[TILE];

  const int tm = blockIdx.y, tn = blockIdx.x;
  const int t = threadIdx.x;
  const int wave = t >> 6, lane = t & 63;
  const int wm = wave >> 1, wn = wave & 1;
  const int c16 = lane & 15, quad = lane >> 4;

  const int rowA = tm * TILE, rowB = tn * TILE;

  f32x4 acc[4][4] = {};

  for (int k0 = 0; k0 < KD; k0 += BK) {
    __syncthreads();
    // stage 128x64 bf16 (= 1024 chunks of 16B) per tile; 4 lds-DMA per wave each
#pragma unroll
    for (int it = 0; it < 4; ++it) {
      const int chunk = it * 256 + t;           // destination chunk position
      const int r = chunk >> 3, cpos = chunk & 7;
      const int c = cpos ^ (r & 7);             // source column chunk (swizzle)
      bf16* dstbase = &lA[(it * 256 + wave * 64) * 8];  // wave-uniform
      load16_to_lds(&zhat[(size_t)(rowA + r) * KD + k0 + c * 8], dstbase);
      bf16* dstbaseB = &lB[(it * 256 + wave * 64) * 8];
      load16_to_lds(&zhat[(size_t)(rowB + r) * KD + k0 + c * 8], dstbaseB);
    }
    __syncthreads();
#pragma unroll
    for (int kk = 0; kk < BK; kk += 32) {
      bf16x8 af[4], bg[4];
#pragma unroll
      for (int mi = 0; mi < 4; ++mi) {
        const int rA = wm * 64 + mi * 16 + c16;
        const int q = (kk >> 3) + quad;
        af[mi] = *(const bf16x8*)&lA[(rA * 8 + (q ^ (rA & 7))) * 8];
      }
#pragma unroll
      for (int ni = 0; ni < 4; ++ni) {
        const int rB = wn * 64 + ni * 16 + c16;
        const int q = (kk >> 3) + quad;
        bg[ni] = *(const bf16x8*)&lB[(rB * 8 + (q ^ (rB & 7))) * 8];
      }
#pragma unroll
      for (int mi = 0; mi < 4; ++mi)
#pragma unroll
        for (int ni = 0; ni < 4; ++ni)
          acc[mi][ni] = __builtin_amdgcn_mfma_f32_16x16x32_bf16(
              af[mi], bg[ni], acc[mi][ni], 0, 0, 0);
    }
  }

  // epilogue: e = exp(2*sim); reduce over this block's 128 columns per row
  if (t < TILE) lrow[t] = 0.f;
  __syncthreads();
#pragma unroll
  for (int mi = 0; mi < 4; ++mi) {
#pragma unroll
    for (int r = 0; r < 4; ++r) {
      float e = 0.f;
#pragma unroll
      for (int ni = 0; ni < 4; ++ni) e += __expf(2.0f * acc[mi][ni][r]);
      // sum across the 16 lanes of this quad (the 16 columns of the MFMA tile)
      e += __shfl_xor(e, 1);
      e += __shfl_xor(e, 2);
      e += __shfl_xor(e, 4);
      e += __shfl_xor(e, 8);
      if (c16 == 0) atomicAdd(&lrow[wm * 64 + mi * 16 + quad * 4 + r], e);
    }
  }
  __syncthreads();
  if (t < TILE) atomicAdd(&rowsum[rowA + t], lrow[t]);
}

// ---------------- finalize: loss contributions ----------------
// one wave handles 16 rows; per row: selfdot (diag removal) + posdot
__global__ __launch_bounds__(256) void nt_finalize(const bf16* __restrict__ zhat,
                                                   const float* __restrict__ rowsum,
                                                   float* __restrict__ acc) {
  const int t = threadIdx.x;
  const int wave = t >> 6, lane = t & 63;
  float local = 0.f;
#pragma unroll
  for (int r = 0; r < 16; ++r) {
    const int i = (blockIdx.x * 4 + wave) * 16 + r;
    const int p = (i + HALF_N) & (NROWS - 1);
    bf16x8 av = *(const bf16x8*)(zhat + (size_t)i * KD + lane * 8);
    bf16x8 bv = *(const bf16x8*)(zhat + (size_t)p * KD + lane * 8);
    float sd = 0.f, cd = 0.f;
#pragma unroll
    for (int j = 0; j < 8; ++j) {
      const float x = (float)av[j];
      sd += x * x;
      cd += x * (float)bv[j];
    }
#pragma unroll
    for (int m = 1; m < 64; m <<= 1) {
      sd += __shfl_xor(sd, m);
      cd += __shfl_xor(cd, m);
    }
    if (lane == 0)
      local += logf(rowsum[i] - __expf(2.f * sd)) - 2.f * cd;
  }
  __shared__ float bsum[4];
  if (lane == 0) bsum[wave] = local;
  __syncthreads();
  if (t == 0) atomicAdd(acc, bsum[0] + bsum[1] + bsum[2] + bsum[3]);
}

__global__ void nt_writeout(const float* __restrict__ acc, float* __restrict__ out) {
  out[0] = acc[0] * (1.0f / NROWS);
}

extern "C" void kernel_launch(void* const* d_in, const int* in_sizes, int n_in,
                              void* d_out, int out_size, void* d_ws, size_t ws_size,
                              hipStream_t stream) {
  const float* zi = (const float*)d_in[0];
  const float* zj = (const float*)d_in[1];
  float* out = (float*)d_out;

  // ws layout: zhat (8192*512 bf16 = 8 MB) | rowsum (8192 f32) | acc (1 f32)
  bf16* zhat = (bf16*)d_ws;
  float* rowsum = (float*)((char*)d_ws + (size_t)NROWS * KD * sizeof(bf16));
  float* acc = rowsum + NROWS;

  hipMemsetAsync(rowsum, 0, (NROWS + 1) * sizeof(float), stream);
  nt_normalize<<<NROWS, 256, 0, stream>>>(zi, zj, zhat);
  dim3 grid(NROWS / TILE, NROWS / TILE);
  nt_gemm<<<grid, 256, 0, stream>>>(zhat, rowsum);
  nt_finalize<<<NROWS / (4 * 16), 256, 0, stream>>>(zhat, rowsum, acc);
  nt_writeout<<<1, 1, 0, stream>>>(acc, out);
}

// Round 3
// 140.034 us; speedup vs baseline: 1.5681x; 1.3641x over previous
//
#include <hip/hip_runtime.h>

// NT-Xent: BATCH=4096, DIM=512, TEMP=0.5
// loss = mean_i [ log(sum_{j!=i} exp(2*cos(z_i,z_j))) - 2*cos(z_i, z_partner) ]
// R3: exploit Gram-matrix symmetry — compute only upper-triangular 128x128
// blocks (2080 of 4096); each off-diagonal block feeds exp row-sums to
// rowsum[rowA+*] AND exp col-sums to rowsum[rowB+*]. exp computed in-place
// in the accumulators (no extra VGPRs). memset/writeout launches folded away.

#define NROWS 8192
#define HALF_N 4096
#define KD 512
#define TILE 128
#define BK 64
#define NT (NROWS / TILE)   // 64 block-tiles per side

typedef __bf16 bf16;
typedef __attribute__((ext_vector_type(8))) __bf16 bf16x8;
typedef __attribute__((ext_vector_type(4))) float f32x4;

__device__ inline void load16_to_lds(const bf16* g, bf16* l) {
  __builtin_amdgcn_global_load_lds((const __attribute__((address_space(1))) void*)g,
                                   (__attribute__((address_space(3))) void*)l,
                                   16, 0, 0);
}

// ---------------- normalize: z (fp32) -> zhat (bf16, unit rows) ----------------
// also zeroes rowsum[] and out[0] (replaces a hipMemsetAsync launch)
__global__ __launch_bounds__(256) void nt_normalize(const float* __restrict__ zi,
                                                    const float* __restrict__ zj,
                                                    bf16* __restrict__ zhat,
                                                    float* __restrict__ rowsum,
                                                    float* __restrict__ out) {
  const int row = blockIdx.x;
  if (threadIdx.x == 0) rowsum[row] = 0.f;
  if (row == 0 && threadIdx.x == 1) out[0] = 0.f;
  const float* src = (row < HALF_N) ? (zi + (size_t)row * KD)
                                    : (zj + (size_t)(row - HALF_N) * KD);
  const int t = threadIdx.x;                 // 256 threads, 2 floats each
  float2 v = ((const float2*)src)[t];
  float ss = v.x * v.x + v.y * v.y;
#pragma unroll
  for (int m = 1; m < 64; m <<= 1) ss += __shfl_xor(ss, m);
  __shared__ float wsum[4];
  if ((t & 63) == 0) wsum[t >> 6] = ss;
  __syncthreads();
  const float tot = wsum[0] + wsum[1] + wsum[2] + wsum[3];
  const float inv = rsqrtf(tot);             // norms ~22.6, EPS irrelevant
  bf16* dst = zhat + (size_t)row * KD + 2 * t;
  dst[0] = (bf16)(v.x * inv);
  dst[1] = (bf16)(v.y * inv);
}

// ---------------- GEMM + exp row/col sums (upper-triangular blocks) ----------
// 128x128 tile per block, 4 waves in 2x2, each wave 4x4 MFMA tiles of 16x16.
// LDS holds 16B chunks at r*8 + (c ^ (r&7)) (XOR swizzle -> 0 bank conflicts).
// Staged with global_load_lds (wave-uniform base + lane*16).
__global__ __launch_bounds__(256) void nt_gemm(const bf16* __restrict__ zhat,
                                               float* __restrict__ rowsum) {
  __shared__ __attribute__((aligned(16))) bf16 lA[TILE * BK];
  __shared__ __attribute__((aligned(16))) bf16 lB[TILE * BK];
  __shared__ float lrow[TILE];
  __shared__ float lcol[TILE];

  // decode linear bid -> (tm, tn) with tn >= tm
  const int bid = blockIdx.x;
  int tm = (int)((float)(2 * NT + 1) * 0.5f -
                 sqrtf((float)(2 * NT + 1) * (float)(2 * NT + 1) * 0.25f - 2.0f * (float)bid));
  if (tm < 0) tm = 0;
  if (tm > NT - 1) tm = NT - 1;
  while ((tm + 1) * NT - ((tm + 1) * tm) / 2 <= bid) ++tm;
  while (tm * NT - (tm * (tm - 1)) / 2 > bid) --tm;
  const int tn = tm + (bid - (tm * NT - (tm * (tm - 1)) / 2));
  const bool diag = (tm == tn);

  const int t = threadIdx.x;
  const int wave = t >> 6, lane = t & 63;
  const int wm = wave >> 1, wn = wave & 1;
  const int c16 = lane & 15, quad = lane >> 4;

  const int rowA = tm * TILE, rowB = tn * TILE;

  f32x4 acc[4][4] = {};

  const bf16* Bt = diag ? lA : lB;   // diagonal blocks: B tile == A tile

  for (int k0 = 0; k0 < KD; k0 += BK) {
    __syncthreads();
    // stage 128x64 bf16 (= 1024 chunks of 16B) per tile
#pragma unroll
    for (int it = 0; it < 4; ++it) {
      const int chunk = it * 256 + t;           // destination chunk position
      const int r = chunk >> 3, cpos = chunk & 7;
      const int c = cpos ^ (r & 7);             // source column chunk (swizzle)
      bf16* dstbase = &lA[(it * 256 + wave * 64) * 8];  // wave-uniform
      load16_to_lds(&zhat[(size_t)(rowA + r) * KD + k0 + c * 8], dstbase);
      if (!diag) {
        bf16* dstbaseB = &lB[(it * 256 + wave * 64) * 8];
        load16_to_lds(&zhat[(size_t)(rowB + r) * KD + k0 + c * 8], dstbaseB);
      }
    }
    __syncthreads();
#pragma unroll
    for (int kk = 0; kk < BK; kk += 32) {
      bf16x8 af[4], bg[4];
#pragma unroll
      for (int mi = 0; mi < 4; ++mi) {
        const int rA = wm * 64 + mi * 16 + c16;
        const int q = (kk >> 3) + quad;
        af[mi] = *(const bf16x8*)&lA[(rA * 8 + (q ^ (rA & 7))) * 8];
      }
#pragma unroll
      for (int ni = 0; ni < 4; ++ni) {
        const int rB = wn * 64 + ni * 16 + c16;
        const int q = (kk >> 3) + quad;
        bg[ni] = *(const bf16x8*)&Bt[(rB * 8 + (q ^ (rB & 7))) * 8];
      }
#pragma unroll
      for (int mi = 0; mi < 4; ++mi)
#pragma unroll
        for (int ni = 0; ni < 4; ++ni)
          acc[mi][ni] = __builtin_amdgcn_mfma_f32_16x16x32_bf16(
              af[mi], bg[ni], acc[mi][ni], 0, 0, 0);
    }
  }

  // ---- epilogue: e = exp(2*sim) in place, then row sums (+ col sums) ----
#pragma unroll
  for (int mi = 0; mi < 4; ++mi)
#pragma unroll
    for (int ni = 0; ni < 4; ++ni)
#pragma unroll
      for (int r = 0; r < 4; ++r)
        acc[mi][ni][r] = __expf(2.0f * acc[mi][ni][r]);

  if (t < TILE) { lrow[t] = 0.f; lcol[t] = 0.f; }
  __syncthreads();

  // row sums: reduce over ni (in-register) and c16 (shfl over lane bits 0-3)
#pragma unroll
  for (int mi = 0; mi < 4; ++mi) {
#pragma unroll
    for (int r = 0; r < 4; ++r) {
      float e = acc[mi][0][r] + acc[mi][1][r] + acc[mi][2][r] + acc[mi][3][r];
      e += __shfl_xor(e, 1);
      e += __shfl_xor(e, 2);
      e += __shfl_xor(e, 4);
      e += __shfl_xor(e, 8);
      if (c16 == 0) atomicAdd(&lrow[wm * 64 + mi * 16 + quad * 4 + r], e);
    }
  }
  // col sums: reduce over mi,r (in-register) and quad (shfl over lane bits 4-5)
  if (!diag) {
#pragma unroll
    for (int ni = 0; ni < 4; ++ni) {
      float g = 0.f;
#pragma unroll
      for (int mi = 0; mi < 4; ++mi)
#pragma unroll
        for (int r = 0; r < 4; ++r) g += acc[mi][ni][r];
      g += __shfl_xor(g, 16);
      g += __shfl_xor(g, 32);
      if (quad == 0) atomicAdd(&lcol[wn * 64 + ni * 16 + c16], g);
    }
  }
  __syncthreads();
  if (t < TILE) {
    atomicAdd(&rowsum[rowA + t], lrow[t]);
    if (!diag) atomicAdd(&rowsum[rowB + t], lcol[t]);
  }
}

// ---------------- finalize: loss contributions ----------------
// one wave handles 4 rows; per row: selfdot (diag removal) + posdot
__global__ __launch_bounds__(256) void nt_finalize(const bf16* __restrict__ zhat,
                                                   const float* __restrict__ rowsum,
                                                   float* __restrict__ out) {
  const int t = threadIdx.x;
  const int wave = t >> 6, lane = t & 63;
  float local = 0.f;
#pragma unroll
  for (int r = 0; r < 4; ++r) {
    const int i = (blockIdx.x * 4 + wave) * 4 + r;
    const int p = (i + HALF_N) & (NROWS - 1);
    bf16x8 av = *(const bf16x8*)(zhat + (size_t)i * KD + lane * 8);
    bf16x8 bv = *(const bf16x8*)(zhat + (size_t)p * KD + lane * 8);
    float sd = 0.f, cd = 0.f;
#pragma unroll
    for (int j = 0; j < 8; ++j) {
      const float x = (float)av[j];
      sd += x * x;
      cd += x * (float)bv[j];
    }
#pragma unroll
    for (int m = 1; m < 64; m <<= 1) {
      sd += __shfl_xor(sd, m);
      cd += __shfl_xor(cd, m);
    }
    if (lane == 0)
      local += logf(rowsum[i] - __expf(2.f * sd)) - 2.f * cd;
  }
  __shared__ float bsum[4];
  if (lane == 0) bsum[wave] = local;
  __syncthreads();
  if (t == 0)
    atomicAdd(out, (bsum[0] + bsum[1] + bsum[2] + bsum[3]) * (1.0f / NROWS));
}

extern "C" void kernel_launch(void* const* d_in, const int* in_sizes, int n_in,
                              void* d_out, int out_size, void* d_ws, size_t ws_size,
                              hipStream_t stream) {
  const float* zi = (const float*)d_in[0];
  const float* zj = (const float*)d_in[1];
  float* out = (float*)d_out;

  // ws layout: zhat (8192*512 bf16 = 8 MB) | rowsum (8192 f32)
  bf16* zhat = (bf16*)d_ws;
  float* rowsum = (float*)((char*)d_ws + (size_t)NROWS * KD * sizeof(bf16));

  nt_normalize<<<NROWS, 256, 0, stream>>>(zi, zj, zhat, rowsum, out);
  nt_gemm<<<NT * (NT + 1) / 2, 256, 0, stream>>>(zhat, rowsum);
  nt_finalize<<<NROWS / 16, 256, 0, stream>>>(zhat, rowsum, out);
}

// Round 4
// 129.349 us; speedup vs baseline: 1.6976x; 1.0826x over previous
//
#include <hip/hip_runtime.h>

// NT-Xent: BATCH=4096, DIM=512, TEMP=0.5
// loss = mean_i [ log(sum_{j!=i} exp(2*cos(z_i,z_j))) - 2*cos(z_i, z_partner) ]
// R4: everything fused into the triangular GEMM —
//  * diagonal removal: diag blocks zero exp(sim_ii) in-register pre-reduction
//  * positive pairs: blocks with tn-tm==32 hold sim[i][i+N] on their block
//    diagonal; harvested pre-exp into a scalar (4*dot per entry)
//  * finalize is now just log(rowsum[i]) + reduce (8192 elems)
//  * normalize rewritten wave-per-row (float4 in, bf16x8 out, shfl-only)

#define NROWS 8192
#define HALF_N 4096
#define KD 512
#define TILE 128
#define BK 64
#define NT (NROWS / TILE)   // 64 block-tiles per side

typedef __bf16 bf16;
typedef __attribute__((ext_vector_type(8))) __bf16 bf16x8;
typedef __attribute__((ext_vector_type(4))) float f32x4;

__device__ inline void load16_to_lds(const bf16* g, bf16* l) {
  __builtin_amdgcn_global_load_lds((const __attribute__((address_space(1))) void*)g,
                                   (__attribute__((address_space(3))) void*)l,
                                   16, 0, 0);
}

// ---------------- normalize: z (fp32) -> zhat (bf16, unit rows) ----------------
// wave-per-row: 4 rows/block, 2048 blocks. Also zeroes rowsum/possum/out.
__global__ __launch_bounds__(256) void nt_normalize(const float* __restrict__ zi,
                                                    const float* __restrict__ zj,
                                                    bf16* __restrict__ zhat,
                                                    float* __restrict__ rowsum,
                                                    float* __restrict__ possum,
                                                    float* __restrict__ out) {
  const int t = threadIdx.x;
  if (t < 4) rowsum[blockIdx.x * 4 + t] = 0.f;
  if (blockIdx.x == 0 && t == 4) { possum[0] = 0.f; out[0] = 0.f; }

  const int wave = t >> 6, lane = t & 63;
  const int row = blockIdx.x * 4 + wave;
  const float* src = (row < HALF_N) ? (zi + (size_t)row * KD)
                                    : (zj + (size_t)(row - HALF_N) * KD);
  const float4 v0 = ((const float4*)src)[lane * 2];
  const float4 v1 = ((const float4*)src)[lane * 2 + 1];
  float ss = v0.x * v0.x + v0.y * v0.y + v0.z * v0.z + v0.w * v0.w +
             v1.x * v1.x + v1.y * v1.y + v1.z * v1.z + v1.w * v1.w;
#pragma unroll
  for (int m = 1; m < 64; m <<= 1) ss += __shfl_xor(ss, m);
  const float inv = rsqrtf(ss);              // norms ~22.6, EPS irrelevant
  bf16x8 o;
  o[0] = (bf16)(v0.x * inv); o[1] = (bf16)(v0.y * inv);
  o[2] = (bf16)(v0.z * inv); o[3] = (bf16)(v0.w * inv);
  o[4] = (bf16)(v1.x * inv); o[5] = (bf16)(v1.y * inv);
  o[6] = (bf16)(v1.z * inv); o[7] = (bf16)(v1.w * inv);
  *(bf16x8*)(zhat + (size_t)row * KD + lane * 8) = o;
}

// ---------------- GEMM + fused epilogue (upper-triangular blocks) ----------
// 128x128 tile per block, 4 waves in 2x2, each wave 4x4 MFMA tiles of 16x16.
// LDS holds 16B chunks at r*8 + (c ^ (r&7)) (XOR swizzle -> 0 bank conflicts).
// Staged with global_load_lds (wave-uniform base + lane*16).
__global__ __launch_bounds__(256) void nt_gemm(const bf16* __restrict__ zhat,
                                               float* __restrict__ rowsum,
                                               float* __restrict__ possum) {
  __shared__ __attribute__((aligned(16))) bf16 lA[TILE * BK];
  __shared__ __attribute__((aligned(16))) bf16 lB[TILE * BK];
  __shared__ float lrow[TILE];
  __shared__ float lcol[TILE];

  // decode linear bid -> (tm, tn) with tn >= tm
  const int bid = blockIdx.x;
  int tm = (int)((float)(2 * NT + 1) * 0.5f -
                 sqrtf((float)(2 * NT + 1) * (float)(2 * NT + 1) * 0.25f - 2.0f * (float)bid));
  if (tm < 0) tm = 0;
  if (tm > NT - 1) tm = NT - 1;
  while ((tm + 1) * NT - ((tm + 1) * tm) / 2 <= bid) ++tm;
  while (tm * NT - (tm * (tm - 1)) / 2 > bid) --tm;
  const int tn = tm + (bid - (tm * NT - (tm * (tm - 1)) / 2));
  const bool diag = (tm == tn);
  const bool isPos = (tn - tm == 32);   // block diagonal holds sim[i][i+N]

  const int t = threadIdx.x;
  const int wave = t >> 6, lane = t & 63;
  const int wm = wave >> 1, wn = wave & 1;
  const int c16 = lane & 15, quad = lane >> 4;

  const int rowA = tm * TILE, rowB = tn * TILE;

  f32x4 acc[4][4] = {};

  const bf16* Bt = diag ? lA : lB;   // diagonal blocks: B tile == A tile

  for (int k0 = 0; k0 < KD; k0 += BK) {
    __syncthreads();
    // stage 128x64 bf16 (= 1024 chunks of 16B) per tile
#pragma unroll
    for (int it = 0; it < 4; ++it) {
      const int chunk = it * 256 + t;           // destination chunk position
      const int r = chunk >> 3, cpos = chunk & 7;
      const int c = cpos ^ (r & 7);             // source column chunk (swizzle)
      bf16* dstbase = &lA[(it * 256 + wave * 64) * 8];  // wave-uniform
      load16_to_lds(&zhat[(size_t)(rowA + r) * KD + k0 + c * 8], dstbase);
      if (!diag) {
        bf16* dstbaseB = &lB[(it * 256 + wave * 64) * 8];
        load16_to_lds(&zhat[(size_t)(rowB + r) * KD + k0 + c * 8], dstbaseB);
      }
    }
    __syncthreads();
#pragma unroll
    for (int kk = 0; kk < BK; kk += 32) {
      bf16x8 af[4], bg[4];
#pragma unroll
      for (int mi = 0; mi < 4; ++mi) {
        const int rA = wm * 64 + mi * 16 + c16;
        const int q = (kk >> 3) + quad;
        af[mi] = *(const bf16x8*)&lA[(rA * 8 + (q ^ (rA & 7))) * 8];
      }
#pragma unroll
      for (int ni = 0; ni < 4; ++ni) {
        const int rB = wn * 64 + ni * 16 + c16;
        const int q = (kk >> 3) + quad;
        bg[ni] = *(const bf16x8*)&Bt[(rB * 8 + (q ^ (rB & 7))) * 8];
      }
#pragma unroll
      for (int mi = 0; mi < 4; ++mi)
#pragma unroll
        for (int ni = 0; ni < 4; ++ni)
          acc[mi][ni] = __builtin_amdgcn_mfma_f32_16x16x32_bf16(
              af[mi], bg[ni], acc[mi][ni], 0, 0, 0);
    }
  }

  // in-tile diagonal ownership: row(quad*4+r) == col(c16) <=> quad==c16>>2, r==c16&3
  const bool ownDiag = (quad == (c16 >> 2));
  const int rdiag = c16 & 3;

  // ---- positive pairs (pre-exp): sum 4*dot over this block's diagonal ----
  if (isPos && wm == wn) {
    float p = 0.f;
    if (ownDiag) {
#pragma unroll
      for (int mi = 0; mi < 4; ++mi) p += acc[mi][mi][rdiag];
    }
#pragma unroll
    for (int m = 1; m < 64; m <<= 1) p += __shfl_xor(p, m);
    if (lane == 0) atomicAdd(possum, 4.0f * p);
  }

  // ---- e = exp(2*sim) in place ----
#pragma unroll
  for (int mi = 0; mi < 4; ++mi)
#pragma unroll
    for (int ni = 0; ni < 4; ++ni)
#pragma unroll
      for (int r = 0; r < 4; ++r)
        acc[mi][ni][r] = __expf(2.0f * acc[mi][ni][r]);

  // ---- diagonal removal (diag blocks): zero exp(sim_ii) ----
  if (diag && wm == wn && ownDiag) {
#pragma unroll
    for (int mi = 0; mi < 4; ++mi) acc[mi][mi][rdiag] = 0.f;
  }

  if (t < TILE) { lrow[t] = 0.f; lcol[t] = 0.f; }
  __syncthreads();

  // row sums: reduce over ni (in-register) and c16 (shfl over lane bits 0-3)
#pragma unroll
  for (int mi = 0; mi < 4; ++mi) {
#pragma unroll
    for (int r = 0; r < 4; ++r) {
      float e = acc[mi][0][r] + acc[mi][1][r] + acc[mi][2][r] + acc[mi][3][r];
      e += __shfl_xor(e, 1);
      e += __shfl_xor(e, 2);
      e += __shfl_xor(e, 4);
      e += __shfl_xor(e, 8);
      if (c16 == 0) atomicAdd(&lrow[wm * 64 + mi * 16 + quad * 4 + r], e);
    }
  }
  // col sums: reduce over mi,r (in-register) and quad (shfl over lane bits 4-5)
  if (!diag) {
#pragma unroll
    for (int ni = 0; ni < 4; ++ni) {
      float g = 0.f;
#pragma unroll
      for (int mi = 0; mi < 4; ++mi)
#pragma unroll
        for (int r = 0; r < 4; ++r) g += acc[mi][ni][r];
      g += __shfl_xor(g, 16);
      g += __shfl_xor(g, 32);
      if (quad == 0) atomicAdd(&lcol[wn * 64 + ni * 16 + c16], g);
    }
  }
  __syncthreads();
  if (t < TILE) {
    atomicAdd(&rowsum[rowA + t], lrow[t]);
    if (!diag) atomicAdd(&rowsum[rowB + t], lcol[t]);
  }
}

// ---------------- finalize: loss = (sum_i log(rowsum_i) - possum) / NROWS ----
__global__ __launch_bounds__(256) void nt_finalize(const float* __restrict__ rowsum,
                                                   const float* __restrict__ possum,
                                                   float* __restrict__ out) {
  const int t = threadIdx.x;
  const int i = blockIdx.x * 256 + t;
  float v = logf(rowsum[i]);
#pragma unroll
  for (int m = 1; m < 64; m <<= 1) v += __shfl_xor(v, m);
  __shared__ float bsum[4];
  if ((t & 63) == 0) bsum[t >> 6] = v;
  __syncthreads();
  if (t == 0) {
    float s = bsum[0] + bsum[1] + bsum[2] + bsum[3];
    if (blockIdx.x == 0) s -= possum[0];
    atomicAdd(out, s * (1.0f / NROWS));
  }
}

extern "C" void kernel_launch(void* const* d_in, const int* in_sizes, int n_in,
                              void* d_out, int out_size, void* d_ws, size_t ws_size,
                              hipStream_t stream) {
  const float* zi = (const float*)d_in[0];
  const float* zj = (const float*)d_in[1];
  float* out = (float*)d_out;

  // ws layout: zhat (8192*512 bf16 = 8 MB) | rowsum (8192 f32) | possum (1 f32)
  bf16* zhat = (bf16*)d_ws;
  float* rowsum = (float*)((char*)d_ws + (size_t)NROWS * KD * sizeof(bf16));
  float* possum = rowsum + NROWS;

  nt_normalize<<<NROWS / 4, 256, 0, stream>>>(zi, zj, zhat, rowsum, possum, out);
  nt_gemm<<<NT * (NT + 1) / 2, 256, 0, stream>>>(zhat, rowsum, possum);
  nt_finalize<<<NROWS / 256, 256, 0, stream>>>(rowsum, possum, out);
}

// Round 5
// 109.902 us; speedup vs baseline: 1.9980x; 1.1769x over previous
//
#include <hip/hip_runtime.h>

// NT-Xent: BATCH=4096, DIM=512, TEMP=0.5
// loss = mean_i [ log(sum_{j!=i} exp(2*cos(z_i,z_j))) - 2*cos(z_i, z_partner) ]
// R5: fp8 MX-scaled GEMM. Rows are unit-norm -> quantize zhat to OCP e4m3 and
// use mfma_scale_f32_16x16x128_f8f6f4 with all scales = 1.0 (E8M0 0x7F):
// 2x MFMA rate vs bf16, half the LDS/HBM bytes, half the staging/read
// instructions, K-loop = 4 iters of BK=128 (one MFMA per tile-pair per iter).
// Triangular blocks + fused diag-removal + positive-pair harvest carried over.

#define NROWS 8192
#define HALF_N 4096
#define KD 512            // elements per row (= 512 B/row in fp8)
#define TILE 128
#define BK 128            // fp8 bytes of K per tile (8 chunks of 16 B per row)
#define NT (NROWS / TILE) // 64 block-tiles per side

typedef unsigned char u8;
typedef __attribute__((ext_vector_type(4))) int i32x4;
typedef __attribute__((ext_vector_type(8))) int i32x8;
typedef __attribute__((ext_vector_type(4))) float f32x4;

__device__ inline void load16_to_lds(const u8* g, u8* l) {
  __builtin_amdgcn_global_load_lds((const __attribute__((address_space(1))) void*)g,
                                   (__attribute__((address_space(3))) void*)l,
                                   16, 0, 0);
}

// ---------------- normalize: z (fp32) -> zq (fp8 e4m3, unit rows) ------------
// wave-per-row: 4 rows/block, 2048 blocks. Also zeroes rowsum/possum/out.
__global__ __launch_bounds__(256) void nt_normalize(const float* __restrict__ zi,
                                                    const float* __restrict__ zj,
                                                    u8* __restrict__ zq,
                                                    float* __restrict__ rowsum,
                                                    float* __restrict__ possum,
                                                    float* __restrict__ out) {
  const int t = threadIdx.x;
  if (t < 4) rowsum[blockIdx.x * 4 + t] = 0.f;
  if (blockIdx.x == 0 && t == 4) { possum[0] = 0.f; out[0] = 0.f; }

  const int wave = t >> 6, lane = t & 63;
  const int row = blockIdx.x * 4 + wave;
  const float* src = (row < HALF_N) ? (zi + (size_t)row * KD)
                                    : (zj + (size_t)(row - HALF_N) * KD);
  const float4 v0 = ((const float4*)src)[lane * 2];
  const float4 v1 = ((const float4*)src)[lane * 2 + 1];
  float ss = v0.x * v0.x + v0.y * v0.y + v0.z * v0.z + v0.w * v0.w +
             v1.x * v1.x + v1.y * v1.y + v1.z * v1.z + v1.w * v1.w;
#pragma unroll
  for (int m = 1; m < 64; m <<= 1) ss += __shfl_xor(ss, m);
  const float inv = rsqrtf(ss);              // norms ~22.6, EPS irrelevant
  int lo = __builtin_amdgcn_cvt_pk_fp8_f32(v0.x * inv, v0.y * inv, 0, false);
  lo = __builtin_amdgcn_cvt_pk_fp8_f32(v0.z * inv, v0.w * inv, lo, true);
  int hi = __builtin_amdgcn_cvt_pk_fp8_f32(v1.x * inv, v1.y * inv, 0, false);
  hi = __builtin_amdgcn_cvt_pk_fp8_f32(v1.z * inv, v1.w * inv, hi, true);
  ((int2*)(zq + (size_t)row * KD))[lane] = make_int2(lo, hi);
}

// ---------------- GEMM + fused epilogue (upper-triangular blocks) ----------
// 128x128 tile per block, 4 waves in 2x2, each wave 4x4 MFMA tiles of 16x16,
// one mfma_scale_f32_16x16x128 per tile-pair per K-iteration (BK=128).
// LDS holds 16B chunks at r*8 + (c ^ (r&7)) (XOR swizzle -> 0 bank conflicts).
// A-frag per lane: m = lane&15, k = quad*32 + j (32 contiguous fp8 bytes =
// chunks 2*quad, 2*quad+1). Scales fixed at 1.0 (0x7F per E8M0 byte).
__global__ __launch_bounds__(256) void nt_gemm(const u8* __restrict__ zq,
                                               float* __restrict__ rowsum,
                                               float* __restrict__ possum) {
  __shared__ __attribute__((aligned(16))) u8 lA[TILE * BK];
  __shared__ __attribute__((aligned(16))) u8 lB[TILE * BK];
  __shared__ float lrow[TILE];
  __shared__ float lcol[TILE];

  // decode linear bid -> (tm, tn) with tn >= tm
  const int bid = blockIdx.x;
  int tm = (int)((float)(2 * NT + 1) * 0.5f -
                 sqrtf((float)(2 * NT + 1) * (float)(2 * NT + 1) * 0.25f - 2.0f * (float)bid));
  if (tm < 0) tm = 0;
  if (tm > NT - 1) tm = NT - 1;
  while ((tm + 1) * NT - ((tm + 1) * tm) / 2 <= bid) ++tm;
  while (tm * NT - (tm * (tm - 1)) / 2 > bid) --tm;
  const int tn = tm + (bid - (tm * NT - (tm * (tm - 1)) / 2));
  const bool diag = (tm == tn);
  const bool isPos = (tn - tm == 32);   // block diagonal holds sim[i][i+N]

  const int t = threadIdx.x;
  const int wave = t >> 6, lane = t & 63;
  const int wm = wave >> 1, wn = wave & 1;
  const int c16 = lane & 15, quad = lane >> 4;

  const int rowA = tm * TILE, rowB = tn * TILE;

  f32x4 acc[4][4] = {};

  const u8* Bt = diag ? lA : lB;   // diagonal blocks: B tile == A tile
  const int q2 = quad * 2;

  for (int k0 = 0; k0 < KD; k0 += BK) {
    __syncthreads();
    // stage 128x128 fp8 (= 1024 chunks of 16B) per tile
#pragma unroll
    for (int it = 0; it < 4; ++it) {
      const int chunk = it * 256 + t;           // destination chunk position
      const int r = chunk >> 3, cpos = chunk & 7;
      const int c = cpos ^ (r & 7);             // source column chunk (swizzle)
      u8* dstA = &lA[(it * 256 + wave * 64) * 16];  // wave-uniform
      load16_to_lds(&zq[(size_t)(rowA + r) * KD + k0 + c * 16], dstA);
      if (!diag) {
        u8* dstB = &lB[(it * 256 + wave * 64) * 16];
        load16_to_lds(&zq[(size_t)(rowB + r) * KD + k0 + c * 16], dstB);
      }
    }
    __syncthreads();

    i32x8 bg[4];
#pragma unroll
    for (int ni = 0; ni < 4; ++ni) {
      const int rB = wn * 64 + ni * 16 + c16;
      const i32x4 bl = *(const i32x4*)&Bt[(rB * 8 + (q2 ^ (rB & 7))) * 16];
      const i32x4 bh = *(const i32x4*)&Bt[(rB * 8 + ((q2 + 1) ^ (rB & 7))) * 16];
      bg[ni] = (i32x8){bl[0], bl[1], bl[2], bl[3], bh[0], bh[1], bh[2], bh[3]};
    }
#pragma unroll
    for (int mi = 0; mi < 4; ++mi) {
      const int rA = wm * 64 + mi * 16 + c16;
      const i32x4 al = *(const i32x4*)&lA[(rA * 8 + (q2 ^ (rA & 7))) * 16];
      const i32x4 ah = *(const i32x4*)&lA[(rA * 8 + ((q2 + 1) ^ (rA & 7))) * 16];
      const i32x8 af = (i32x8){al[0], al[1], al[2], al[3], ah[0], ah[1], ah[2], ah[3]};
#pragma unroll
      for (int ni = 0; ni < 4; ++ni)
        acc[mi][ni] = __builtin_amdgcn_mfma_scale_f32_16x16x128_f8f6f4(
            af, bg[ni], acc[mi][ni],
            0, 0,                    // cbsz=fp8(e4m3), blgp=fp8(e4m3)
            0, 0x7F7F7F7F,           // scale A: opsel 0, E8M0 1.0
            0, 0x7F7F7F7F);          // scale B: opsel 0, E8M0 1.0
    }
  }

  // in-tile diagonal ownership: row(quad*4+r) == col(c16) <=> quad==c16>>2, r==c16&3
  const bool ownDiag = (quad == (c16 >> 2));
  const int rdiag = c16 & 3;

  // ---- positive pairs (pre-exp): sum 4*dot over this block's diagonal ----
  if (isPos && wm == wn) {
    float p = 0.f;
    if (ownDiag) {
#pragma unroll
      for (int mi = 0; mi < 4; ++mi) p += acc[mi][mi][rdiag];
    }
#pragma unroll
    for (int m = 1; m < 64; m <<= 1) p += __shfl_xor(p, m);
    if (lane == 0) atomicAdd(possum, 4.0f * p);
  }

  // ---- e = exp(2*sim) in place ----
#pragma unroll
  for (int mi = 0; mi < 4; ++mi)
#pragma unroll
    for (int ni = 0; ni < 4; ++ni)
#pragma unroll
      for (int r = 0; r < 4; ++r)
        acc[mi][ni][r] = __expf(2.0f * acc[mi][ni][r]);

  // ---- diagonal removal (diag blocks): zero exp(sim_ii) ----
  if (diag && wm == wn && ownDiag) {
#pragma unroll
    for (int mi = 0; mi < 4; ++mi) acc[mi][mi][rdiag] = 0.f;
  }

  if (t < TILE) { lrow[t] = 0.f; lcol[t] = 0.f; }
  __syncthreads();

  // row sums: reduce over ni (in-register) and c16 (shfl over lane bits 0-3)
#pragma unroll
  for (int mi = 0; mi < 4; ++mi) {
#pragma unroll
    for (int r = 0; r < 4; ++r) {
      float e = acc[mi][0][r] + acc[mi][1][r] + acc[mi][2][r] + acc[mi][3][r];
      e += __shfl_xor(e, 1);
      e += __shfl_xor(e, 2);
      e += __shfl_xor(e, 4);
      e += __shfl_xor(e, 8);
      if (c16 == 0) atomicAdd(&lrow[wm * 64 + mi * 16 + quad * 4 + r], e);
    }
  }
  // col sums: reduce over mi,r (in-register) and quad (shfl over lane bits 4-5)
  if (!diag) {
#pragma unroll
    for (int ni = 0; ni < 4; ++ni) {
      float g = 0.f;
#pragma unroll
      for (int mi = 0; mi < 4; ++mi)
#pragma unroll
        for (int r = 0; r < 4; ++r) g += acc[mi][ni][r];
      g += __shfl_xor(g, 16);
      g += __shfl_xor(g, 32);
      if (quad == 0) atomicAdd(&lcol[wn * 64 + ni * 16 + c16], g);
    }
  }
  __syncthreads();
  if (t < TILE) {
    atomicAdd(&rowsum[rowA + t], lrow[t]);
    if (!diag) atomicAdd(&rowsum[rowB + t], lcol[t]);
  }
}

// ---------------- finalize: loss = (sum_i log(rowsum_i) - possum) / NROWS ----
__global__ __launch_bounds__(256) void nt_finalize(const float* __restrict__ rowsum,
                                                   const float* __restrict__ possum,
                                                   float* __restrict__ out) {
  const int t = threadIdx.x;
  const int i = blockIdx.x * 256 + t;
  float v = logf(rowsum[i]);
#pragma unroll
  for (int m = 1; m < 64; m <<= 1) v += __shfl_xor(v, m);
  __shared__ float bsum[4];
  if ((t & 63) == 0) bsum[t >> 6] = v;
  __syncthreads();
  if (t == 0) {
    float s = bsum[0] + bsum[1] + bsum[2] + bsum[3];
    if (blockIdx.x == 0) s -= possum[0];
    atomicAdd(out, s * (1.0f / NROWS));
  }
}

extern "C" void kernel_launch(void* const* d_in, const int* in_sizes, int n_in,
                              void* d_out, int out_size, void* d_ws, size_t ws_size,
                              hipStream_t stream) {
  const float* zi = (const float*)d_in[0];
  const float* zj = (const float*)d_in[1];
  float* out = (float*)d_out;

  // ws layout: zq (8192*512 fp8 = 4 MB) | rowsum (8192 f32) | possum (1 f32)
  u8* zq = (u8*)d_ws;
  float* rowsum = (float*)((char*)d_ws + (size_t)NROWS * KD);
  float* possum = rowsum + NROWS;

  nt_normalize<<<NROWS / 4, 256, 0, stream>>>(zi, zj, zq, rowsum, possum, out);
  nt_gemm<<<NT * (NT + 1) / 2, 256, 0, stream>>>(zq, rowsum, possum);
  nt_finalize<<<NROWS / 256, 256, 0, stream>>>(rowsum, possum, out);
}